// Round 12
// baseline (697.094 us; speedup 1.0000x reference)
//
#include <hip/hip_runtime.h>
#include <cstdint>
#include <cstddef>

typedef _Float16 half8 __attribute__((ext_vector_type(8)));
typedef _Float16 half4_t __attribute__((ext_vector_type(4)));
typedef _Float16 half2_t __attribute__((ext_vector_type(2)));
typedef float f32x4 __attribute__((ext_vector_type(4)));
typedef unsigned int uint4_t __attribute__((ext_vector_type(4)));
typedef unsigned int uint2_t __attribute__((ext_vector_type(2)));

#define LOG2E 1.4426950408889634f

// async global->LDS, 16B per lane. LDS dest must be wave-uniform base + lane*16.
__device__ __forceinline__ void async16(const void* g, void* l) {
  __builtin_amdgcn_global_load_lds((const __attribute__((address_space(1))) void*)g,
                                   (__attribute__((address_space(3))) void*)l,
                                   16, 0, 0);
}

__device__ __forceinline__ f32x4 vmax4(f32x4 a, f32x4 b) {
  f32x4 r;
  r[0] = fmaxf(a[0], b[0]); r[1] = fmaxf(a[1], b[1]);
  r[2] = fmaxf(a[2], b[2]); r[3] = fmaxf(a[3], b[3]);
  return r;
}

// fmaxf(fmaxf(a,b),c) fuses to v_max3_f32
__device__ __forceinline__ f32x4 vmax4_3(f32x4 a, f32x4 b, f32x4 c) {
  f32x4 r;
  r[0] = fmaxf(fmaxf(a[0], b[0]), c[0]);
  r[1] = fmaxf(fmaxf(a[1], b[1]), c[1]);
  r[2] = fmaxf(fmaxf(a[2], b[2]), c[2]);
  r[3] = fmaxf(fmaxf(a[3], b[3]), c[3]);
  return r;
}

__device__ __forceinline__ half2_t pk_cvt(float a, float b) {
  return __builtin_bit_cast(half2_t, __builtin_amdgcn_cvt_pkrtz(a, b));
}

// raw v_exp_f32 (skips OCML denormal fixup; args are <= 0, outputs in [0,1])
__device__ __forceinline__ float fexp2(float x) { return __builtin_amdgcn_exp2f(x); }

// gfx950 cross-lane swaps via BUILTINS (not inline asm!).
// r5 lesson: raw asm permlane is schedule-dependent-broken (VALU->permlane
// hazard invisible through an asm blob); builtins emit real MIs so the
// backend inserts required wait states under any schedule.
__device__ __forceinline__ void plswap32(unsigned& a, unsigned& b) {
  uint2_t r = __builtin_amdgcn_permlane32_swap(a, b, false, false);
  a = r[0]; b = r[1];
}
__device__ __forceinline__ void plswap16(unsigned& a, unsigned& b) {
  uint2_t r = __builtin_amdgcn_permlane16_swap(a, b, false, false);
  a = r[0]; b = r[1];
}

// ---------------- fp32 -> fp16 convert ----------------
__global__ __launch_bounds__(256) void cvt_f32_f16(const float* __restrict__ in,
                                                   _Float16* __restrict__ out, int n) {
  int i = (blockIdx.x * 256 + threadIdx.x) * 8;
  if (i + 7 < n) {
    f32x4 a = *(const f32x4*)(in + i);
    f32x4 b = *(const f32x4*)(in + i + 4);
    half8 h;
    h[0] = (_Float16)a[0]; h[1] = (_Float16)a[1];
    h[2] = (_Float16)a[2]; h[3] = (_Float16)a[3];
    h[4] = (_Float16)b[0]; h[5] = (_Float16)b[1];
    h[6] = (_Float16)b[2]; h[7] = (_Float16)b[3];
    *(half8*)(out + i) = h;
  }
}

// 4 weight matrices (1M elems each) in one launch
__global__ __launch_bounds__(256) void cvt_w4(
    const float* __restrict__ a, const float* __restrict__ b,
    const float* __restrict__ c, const float* __restrict__ d,
    _Float16* __restrict__ oa, _Float16* __restrict__ ob,
    _Float16* __restrict__ oc, _Float16* __restrict__ od) {
  int seg = blockIdx.x >> 9;
  const float* src = (seg == 0) ? a : (seg == 1) ? b : (seg == 2) ? c : d;
  _Float16* dst = (seg == 0) ? oa : (seg == 1) ? ob : (seg == 2) ? oc : od;
  int i = ((blockIdx.x & 511) * 256 + threadIdx.x) * 8;
  f32x4 x0 = *(const f32x4*)(src + i);
  f32x4 x1 = *(const f32x4*)(src + i + 4);
  half8 h;
  h[0] = (_Float16)x0[0]; h[1] = (_Float16)x0[1];
  h[2] = (_Float16)x0[2]; h[3] = (_Float16)x0[3];
  h[4] = (_Float16)x1[0]; h[5] = (_Float16)x1[1];
  h[6] = (_Float16)x1[2]; h[7] = (_Float16)x1[3];
  *(half8*)(dst + i) = h;
}

// ---------------- shared 128x128x1024 NT-GEMM mainloop ----------------
// Double-buffered LDS, issue-early / sync-late (T3-minimum pipeline).
__device__ __forceinline__ void gemm128_mainloop(const _Float16* __restrict__ Ap,
                                                 const _Float16* __restrict__ Wp,
                                                 _Float16* As, _Float16* Bs,
                                                 f32x4 (&acc)[4][4]) {
  const int tid = threadIdx.x;
  const int lane = tid & 63;
  const int wid = tid >> 6;
  const int c = lane & 15, quad = lane >> 4;
  const int wm0 = (wid >> 1) * 64, wn0 = (wid & 1) * 64;
  const _Float16* ga0 = Ap + (size_t)(tid >> 2) * 1024 + (tid & 3) * 8;
  const _Float16* ga1 = ga0 + (size_t)64 * 1024;
  const _Float16* gb0 = Wp + (size_t)(tid >> 2) * 1024 + (tid & 3) * 8;
  const _Float16* gb1 = gb0 + (size_t)64 * 1024;
  // prologue: stage k0=0 into buffer 0
  async16(ga0, &As[tid * 8]);
  async16(ga1, &As[(tid + 256) * 8]);
  async16(gb0, &Bs[tid * 8]);
  async16(gb1, &Bs[(tid + 256) * 8]);
  __syncthreads();
  for (int k0 = 0; k0 < 1024; k0 += 32) {
    const int curo = ((k0 >> 5) & 1) * (128 * 32);
    if (k0 + 32 < 1024) {
      const int nxto = (128 * 32) - curo;
      async16(ga0 + k0 + 32, &As[nxto + tid * 8]);
      async16(ga1 + k0 + 32, &As[nxto + (tid + 256) * 8]);
      async16(gb0 + k0 + 32, &Bs[nxto + tid * 8]);
      async16(gb1 + k0 + 32, &Bs[nxto + (tid + 256) * 8]);
    }
    half8 af[4], bf[4];
#pragma unroll
    for (int i = 0; i < 4; ++i)
      af[i] = *(const half8*)&As[curo + (wm0 + i * 16 + c) * 32 + quad * 8];
#pragma unroll
    for (int j = 0; j < 4; ++j)
      bf[j] = *(const half8*)&Bs[curo + (wn0 + j * 16 + c) * 32 + quad * 8];
#pragma unroll
    for (int i = 0; i < 4; ++i)
#pragma unroll
      for (int j = 0; j < 4; ++j)
        acc[i][j] = __builtin_amdgcn_mfma_f32_16x16x32_f16(af[i], bf[j], acc[i][j], 0, 0, 0);
    __syncthreads();  // drains next-tile loads (issued a full compute phase ago)
  }
}

// ---------------- QKV projection ----------------
// z=0/1: (B,H,T,64); z=2: V stored TRANSPOSED (B,H,64,T).
// Round-12: coalesced epilogues. The old epilogue scatter-wrote 96MB with
// heavy amplification (z=0/1: 64 scalar 2B stores/thread in 32B segments;
// z=2: 8B chunks at 8KB stride). Now: acc is staged into a 128x128 f16 tile
// in the (dead after mainloop) 32KB As/Bs pool, then each thread writes one
// contiguous 128B run (8x dwordx4) — full sectors, 8 store instrs, no RFO
// amplification (same fix that cut fa's WRITE 295->77MB in r3).
__global__ __launch_bounds__(256, 2) void gemm_qkv(
    const _Float16* __restrict__ A,
    const _Float16* __restrict__ Wq, const _Float16* __restrict__ Wk,
    const _Float16* __restrict__ Wv,
    const float* __restrict__ Bq, const float* __restrict__ Bk,
    const float* __restrict__ Bv,
    _Float16* __restrict__ Qo, _Float16* __restrict__ Ko, _Float16* __restrict__ VoT) {
  __shared__ __align__(16) _Float16 smem[16384];  // 32KB: mainloop As|Bs, then epilogue tile
  const int z = blockIdx.z;
  const _Float16* W = (z == 0) ? Wq : (z == 1) ? Wk : Wv;
  const float* bias = (z == 0) ? Bq : (z == 1) ? Bk : Bv;
  const float scale = (z == 0) ? LOG2E : 1.0f;  // fold exp->exp2 into Q
  const int m0 = blockIdx.x * 128, n0 = blockIdx.y * 128;
  f32x4 acc[4][4] = {};
  gemm128_mainloop(A + (size_t)m0 * 1024, W + (size_t)n0 * 1024, smem, smem + 8192, acc);
  // mainloop ends with __syncthreads(): all LDS reads done, smem reusable.
  const int tid = threadIdx.x;
  const int lane = tid & 63, wid = tid >> 6;
  const int c = lane & 15, quad = lane >> 4;
  const int wm0 = (wid >> 1) * 64, wn0 = (wid & 1) * 64;
  _Float16* tile = smem;  // 128x128 f16 = 32KB
  if (z == 2) {
    // stage transposed [n_local][m_local] (m contiguous -> half4 per (i,j))
#pragma unroll
    for (int j = 0; j < 4; ++j) {
      int nl = wn0 + j * 16 + c;
      float bvv = bias[n0 + nl];
#pragma unroll
      for (int i = 0; i < 4; ++i) {
        int ml = wm0 + i * 16 + quad * 4;
        half4_t hv;
#pragma unroll
        for (int r = 0; r < 4; ++r) hv[r] = (_Float16)(acc[i][j][r] + bvv);
        *(half4_t*)&tile[nl * 128 + ml] = hv;
      }
    }
    __syncthreads();
    {
      int nrow = tid >> 1, part = tid & 1;  // n_local, m-half
      int n = n0 + nrow;
      int h = n >> 6, d = n & 63;
      int m = m0 + part * 64;
      int bb = m >> 12, t = m & 4095;  // m0 is 128-aligned: same bb both parts
      _Float16* dst = VoT + (((size_t)((bb * 16 + h) * 64 + d)) << 12) + t;
      const half8* src = (const half8*)&tile[nrow * 128 + part * 64];
      half8* d8 = (half8*)dst;
#pragma unroll
      for (int k = 0; k < 8; ++k) d8[k] = src[k];
    }
  } else {
    _Float16* out = (z == 0) ? Qo : Ko;
    // stage [m_local][n_local]
#pragma unroll
    for (int j = 0; j < 4; ++j) {
      int nl = wn0 + j * 16 + c;
      float bvv = bias[n0 + nl];
#pragma unroll
      for (int i = 0; i < 4; ++i) {
        int ml = wm0 + i * 16 + quad * 4;
#pragma unroll
        for (int r = 0; r < 4; ++r)
          tile[(ml + r) * 128 + nl] = (_Float16)((acc[i][j][r] + bvv) * scale);
      }
    }
    __syncthreads();
    {
      int row = tid >> 1, part = tid & 1;  // t_local, head-half
      int m = m0 + row;
      int bb = m >> 12, t = m & 4095;
      int h = (n0 >> 6) + part;
      _Float16* dst = out + (((size_t)(bb * 16 + h) * 4096 + t) << 6);
      const half8* src = (const half8*)&tile[row * 128 + part * 64];
      half8* d8 = (half8*)dst;
#pragma unroll
      for (int k = 0; k < 8; ++k) d8[k] = src[k];
    }
  }
}

// ---------------- out projection, fp32 epilogue ----------------
// fp32 rows: lane-contiguous 64B segments, no amplification — left as-is.
__global__ __launch_bounds__(256, 2) void gemm_out(
    const _Float16* __restrict__ A, const _Float16* __restrict__ W,
    const float* __restrict__ bias, float* __restrict__ out) {
  __shared__ __align__(16) _Float16 As[2 * 128 * 32];
  __shared__ __align__(16) _Float16 Bs[2 * 128 * 32];
  const int m0 = blockIdx.x * 128, n0 = blockIdx.y * 128;
  f32x4 acc[4][4] = {};
  gemm128_mainloop(A + (size_t)m0 * 1024, W + (size_t)n0 * 1024, As, Bs, acc);
  const int tid = threadIdx.x;
  const int lane = tid & 63, wid = tid >> 6;
  const int c = lane & 15, quad = lane >> 4;
  const int wm0 = (wid >> 1) * 64, wn0 = (wid & 1) * 64;
#pragma unroll
  for (int j = 0; j < 4; ++j) {
    int n = n0 + wn0 + j * 16 + c;
    float bv = bias[n];
#pragma unroll
    for (int i = 0; i < 4; ++i) {
      int mb = m0 + wm0 + i * 16 + quad * 4;
#pragma unroll
      for (int r = 0; r < 4; ++r) {
        int m = mb + r;
        out[(size_t)m * 1024 + n] = acc[i][j][r] + bv;
      }
    }
  }
}

// ---------------- fa tile step: compute buf CB, prefetch j+1 into buf NB ----
// CB/NB are template constants so LDS addresses fold into the 16-bit DS
// offset immediates (r9 lesson: runtime offsets cost +5 VALUBusy pts, +25us).
// L row-sum on the MATRIX pipe: one extra PV MFMA per ks-chunk with an
// all-ones B operand accumulates lacc[r] = sum_k P[q=quad*4+r][k] in C/D
// layout = the epilogue's layout (r11).
template <int CB, int NB>
__device__ __forceinline__ void fa_step(
    int j, int tid, int c, int quad,
    const _Float16* __restrict__ Kh, const _Float16* __restrict__ Vh,
    _Float16* Ks, _Float16* VsT,
    const half8 (&qf)[2], f32x4 (&oacc)[4], float& M, f32x4& L4) {
  // prefetch tile j+1 into the other buffer (its readers finished before the
  // previous iteration's end barrier)
  if (j + 1 < 32) {
#pragma unroll
    for (int it = 0; it < 2; ++it) {
      int cidx = it * 512 + tid;
      int row = cidx >> 3, ck = (cidx & 7) ^ (row & 7);
      async16(Kh + (size_t)((j + 1) * 128 + row) * 64 + ck * 8, &Ks[NB + cidx * 8]);
    }
#pragma unroll
    for (int it = 0; it < 2; ++it) {
      int cidx = it * 512 + tid;
      int d = cidx >> 4, ck = (cidx & 15) ^ (d & 7);
      async16(Vh + (size_t)d * 4096 + (j + 1) * 128 + ck * 8, &VsT[NB + cidx * 8]);
    }
  }

  // S^T = K * Q^T (128 keys x 16 q-rows)
  f32x4 s[8];
#pragma unroll
  for (int j8 = 0; j8 < 8; ++j8) {
    int krow = j8 * 16 + c;
    int ck = quad ^ (c & 7);
    half8 kf = *(const half8*)&Ks[CB + krow * 64 + ck * 8];
    f32x4 z = {};
    s[j8] = __builtin_amdgcn_mfma_f32_16x16x32_f16(kf, qf[0], z, 0, 0, 0);
  }
#pragma unroll
  for (int j8 = 0; j8 < 8; ++j8) {
    int krow = j8 * 16 + c;
    int ck = (4 + quad) ^ (c & 7);
    half8 kf = *(const half8*)&Ks[CB + krow * 64 + ck * 8];
    s[j8] = __builtin_amdgcn_mfma_f32_16x16x32_f16(kf, qf[1], s[j8], 0, 0, 0);
  }

  // running max (max3 tree + cross-quad); M/al are per-lane for row c
  f32x4 t0 = vmax4_3(s[0], s[1], s[2]);
  f32x4 t1 = vmax4_3(s[3], s[4], s[5]);
  f32x4 t2 = vmax4_3(t0, t1, vmax4(s[6], s[7]));
  float mx = fmaxf(fmaxf(fmaxf(t2[0], t2[1]), t2[2]), t2[3]);
  mx = fmaxf(mx, __shfl_xor(mx, 16));
  mx = fmaxf(mx, __shfl_xor(mx, 32));
  float Mn = fmaxf(M, mx);
  float al = fexp2(M - Mn);
  M = Mn;

  const half8 vones = {(_Float16)1.f, (_Float16)1.f, (_Float16)1.f, (_Float16)1.f,
                       (_Float16)1.f, (_Float16)1.f, (_Float16)1.f, (_Float16)1.f};
  f32x4 lacc = {};  // row-sum accumulator (matrix pipe), row = quad*4+r

  // exp + pack + in-register transpose (permlane) + PV, 32 keys per chunk
#pragma unroll
  for (int ks = 0; ks < 4; ++ks) {
    f32x4 a0 = s[2 * ks] - Mn;
    f32x4 a1 = s[2 * ks + 1] - Mn;
    f32x4 p0, p1;
    p0[0] = fexp2(a0[0]); p0[1] = fexp2(a0[1]);
    p0[2] = fexp2(a0[2]); p0[3] = fexp2(a0[3]);
    p1[0] = fexp2(a1[0]); p1[1] = fexp2(a1[1]);
    p1[2] = fexp2(a1[2]); p1[3] = fexp2(a1[3]);
    unsigned w0 = __builtin_bit_cast(unsigned, pk_cvt(p0[0], p0[1]));
    unsigned w1 = __builtin_bit_cast(unsigned, pk_cvt(p0[2], p0[3]));
    unsigned w2 = __builtin_bit_cast(unsigned, pk_cvt(p1[0], p1[1]));
    unsigned w3 = __builtin_bit_cast(unsigned, pk_cvt(p1[2], p1[3]));
    plswap32(w0, w2);
    plswap32(w1, w3);
    plswap16(w0, w2);
    plswap16(w1, w3);
    uint4_t uw = {w0, w1, w2, w3};
    half8 pf = __builtin_bit_cast(half8, uw);
    lacc = __builtin_amdgcn_mfma_f32_16x16x32_f16(pf, vones, lacc, 0, 0, 0);
#pragma unroll
    for (int n = 0; n < 4; ++n) {
      int d = n * 16 + c;
      int ck = (ks * 4 + quad) ^ (d & 7);
      half8 vf = *(const half8*)&VsT[CB + d * 128 + ck * 8];
      oacc[n] = __builtin_amdgcn_mfma_f32_16x16x32_f16(pf, vf, oacc[n], 0, 0, 0);
    }
  }

  // L recursion per row (L4[r] tracks row quad*4+r; al held by lane quad*4+r)
#pragma unroll
  for (int r = 0; r < 4; ++r) {
    float alr = __shfl(al, quad * 4 + r);
    L4[r] = alr * L4[r] + lacc[r];  // L IS rescaled; O is NOT (faithful to reference)
  }

  __syncthreads();  // drains the j+1 prefetch (issued a full compute ago);
                    // joins all waves' reads of buf CB before it's reused
}

// ---------------- fused flash attention (buggy-variant-faithful) ----------------
// K/V double-buffer with compile-time buffer offsets (unroll-by-2), 1
// barrier/iter, 8 waves x 16 q-rows, 512 threads, LDS 64KB -> 2 blocks/CU,
// permlane P-transpose, matrix-pipe L row-sum, XCD swizzle, coalesced
// epilogue, raw exp2, KVBLK=128 (semantics: running-max sequence matches
// reference BKV scan).
__global__ __launch_bounds__(512, 4) void fa_kernel(
    const _Float16* __restrict__ Qg, const _Float16* __restrict__ Kg,
    const _Float16* __restrict__ VgT, _Float16* __restrict__ Og) {
  __shared__ __align__(16) _Float16 Ks[2 * 128 * 64];   // dbuf K; buf1 holds Q at start; buf0 = O staging at end
  __shared__ __align__(16) _Float16 VsT[2 * 64 * 128];  // dbuf V (d, key), swizzled

  const int tid = threadIdx.x;
  const int lane = tid & 63, wid = tid >> 6;   // wid 0..7
  const int c = lane & 15, quad = lane >> 4;
  // XCD-aware remap: xcd = bid&7 gets swz in [xcd*256, xcd*256+256) =
  // heads [xcd*8, xcd*8+8), all 32 qt each. Bijective (2048 % 8 == 0).
  const int bid = blockIdx.x;
  const int swz = (bid & 7) * 256 + (bid >> 3);
  const int bh = swz >> 5, qt = swz & 31;
  const int b = bh >> 4, h = bh & 15;
  const size_t hoff = (size_t)bh * 4096 * 64;
  const _Float16* Qh = Qg + hoff + (size_t)qt * 128 * 64;
  const _Float16* Kh = Kg + hoff;
  const _Float16* Vh = VgT + hoff;  // (64, 4096)

  // stage Q tile (128x64) into Ks BUF1, per-row chunk swizzle (512 thr -> 2 its)
#pragma unroll
  for (int it = 0; it < 2; ++it) {
    int cidx = it * 512 + tid;
    int row = cidx >> 3, ck = (cidx & 7) ^ (row & 7);
    async16(Qh + row * 64 + ck * 8, &Ks[8192 + cidx * 8]);
  }
  __syncthreads();

  const int wq0 = wid * 16;  // this wave's 16 q-rows
  half8 qf[2];
#pragma unroll
  for (int kk = 0; kk < 2; ++kk) {
    int row = wq0 + c;
    int ck = (kk * 4 + quad) ^ (c & 7);
    qf[kk] = *(const half8*)&Ks[8192 + row * 64 + ck * 8];
  }

  // issue K/V(0) into buf0 (no race with buf1 Q reads above)
#pragma unroll
  for (int it = 0; it < 2; ++it) {
    int cidx = it * 512 + tid;
    int row = cidx >> 3, ck = (cidx & 7) ^ (row & 7);
    async16(Kh + (size_t)row * 64 + ck * 8, &Ks[cidx * 8]);
  }
#pragma unroll
  for (int it = 0; it < 2; ++it) {
    int cidx = it * 512 + tid;
    int d = cidx >> 4, ck = (cidx & 15) ^ (d & 7);
    async16(Vh + (size_t)d * 4096 + ck * 8, &VsT[cidx * 8]);
  }
  __syncthreads();  // drains K/V(0); all waves done reading Q from buf1

  f32x4 oacc[4] = {};
  f32x4 L4 = {};
  float M = -__builtin_inff();

  for (int jj = 0; jj < 16; ++jj) {
    fa_step<0, 8192>(2 * jj, tid, c, quad, Kh, Vh, Ks, VsT, qf, oacc, M, L4);
    fa_step<8192, 0>(2 * jj + 1, tid, c, quad, Kh, Vh, Ks, VsT, qf, oacc, M, L4);
  }

  // ---- epilogue: O/L, staged through Ks buf0 for coalesced 128B-row stores ----
  // L4[r] already holds L for row quad*4+r (same layout as oacc) — no shfl.
#pragma unroll
  for (int r = 0; r < 4; ++r) {
    float inv = 1.0f / L4[r];
    int row = wq0 + quad * 4 + r;
#pragma unroll
    for (int n = 0; n < 4; ++n)
      Ks[row * 64 + n * 16 + c] = (_Float16)(oacc[n][r] * inv);
  }
  __syncthreads();
  {
    int row = tid >> 2, part = tid & 3;  // 512 threads: 4 threads per 128B row
    int t = qt * 128 + row;
    size_t base = (((size_t)(b * 4096 + t)) << 10) + h * 64 + part * 16;
    const half8* srcp = (const half8*)&Ks[row * 64 + part * 16];
    half8* dstp = (half8*)(Og + base);
    dstp[0] = srcp[0];
    dstp[1] = srcp[1];
  }
}

// ---------------- launcher ----------------
extern "C" void kernel_launch(void* const* d_in, const int* in_sizes, int n_in,
                              void* d_out, int out_size, void* d_ws, size_t ws_size,
                              hipStream_t stream) {
  const float* x = (const float*)d_in[0];
  const float* wq = (const float*)d_in[1];
  const float* bq = (const float*)d_in[2];
  const float* wk = (const float*)d_in[3];
  const float* bk = (const float*)d_in[4];
  const float* wv = (const float*)d_in[5];
  const float* bv = (const float*)d_in[6];
  const float* wo = (const float*)d_in[7];
  const float* bo = (const float*)d_in[8];

  char* ws = (char*)d_ws;
  const size_t MB = 1024 * 1024;
  _Float16* xb = (_Float16*)(ws);               // 32MB; dead after gemm_qkv -> reused as Oatt
  _Float16* wq16 = (_Float16*)(ws + 32 * MB);
  _Float16* wk16 = (_Float16*)(ws + 34 * MB);
  _Float16* wv16 = (_Float16*)(ws + 36 * MB);
  _Float16* wo16 = (_Float16*)(ws + 38 * MB);
  _Float16* Qg = (_Float16*)(ws + 40 * MB);     // (B,H,T,64)
  _Float16* Kg = (_Float16*)(ws + 72 * MB);     // (B,H,T,64)
  _Float16* VgT = (_Float16*)(ws + 104 * MB);   // (B,H,64,T) written directly by gemm_qkv
  _Float16* Oatt = xb;                          // (B,T,1024)

  cvt_f32_f16<<<8192, 256, 0, stream>>>(x, xb, 16777216);
  cvt_w4<<<2048, 256, 0, stream>>>(wq, wk, wv, wo, wq16, wk16, wv16, wo16);

  gemm_qkv<<<dim3(128, 8, 3), 256, 0, stream>>>(xb, wq16, wk16, wv16,
                                                bq, bk, bv, Qg, Kg, VgT);
  fa_kernel<<<dim3(2048), 512, 0, stream>>>(Qg, Kg, VgT, Oatt);
  gemm_out<<<dim3(128, 8), 256, 0, stream>>>(Oatt, wo16, bo, (float*)d_out);
}

// Round 13
// 675.899 us; speedup vs baseline: 1.0314x; 1.0314x over previous
//
#include <hip/hip_runtime.h>
#include <cstdint>
#include <cstddef>

typedef _Float16 half8 __attribute__((ext_vector_type(8)));
typedef _Float16 half4_t __attribute__((ext_vector_type(4)));
typedef _Float16 half2_t __attribute__((ext_vector_type(2)));
typedef float f32x4 __attribute__((ext_vector_type(4)));
typedef unsigned int uint4_t __attribute__((ext_vector_type(4)));
typedef unsigned int uint2_t __attribute__((ext_vector_type(2)));

#define LOG2E 1.4426950408889634f

// async global->LDS, 16B per lane. LDS dest must be wave-uniform base + lane*16.
__device__ __forceinline__ void async16(const void* g, void* l) {
  __builtin_amdgcn_global_load_lds((const __attribute__((address_space(1))) void*)g,
                                   (__attribute__((address_space(3))) void*)l,
                                   16, 0, 0);
}

__device__ __forceinline__ f32x4 vmax4(f32x4 a, f32x4 b) {
  f32x4 r;
  r[0] = fmaxf(a[0], b[0]); r[1] = fmaxf(a[1], b[1]);
  r[2] = fmaxf(a[2], b[2]); r[3] = fmaxf(a[3], b[3]);
  return r;
}

// fmaxf(fmaxf(a,b),c) fuses to v_max3_f32
__device__ __forceinline__ f32x4 vmax4_3(f32x4 a, f32x4 b, f32x4 c) {
  f32x4 r;
  r[0] = fmaxf(fmaxf(a[0], b[0]), c[0]);
  r[1] = fmaxf(fmaxf(a[1], b[1]), c[1]);
  r[2] = fmaxf(fmaxf(a[2], b[2]), c[2]);
  r[3] = fmaxf(fmaxf(a[3], b[3]), c[3]);
  return r;
}

__device__ __forceinline__ half2_t pk_cvt(float a, float b) {
  return __builtin_bit_cast(half2_t, __builtin_amdgcn_cvt_pkrtz(a, b));
}

// raw v_exp_f32 (skips OCML denormal fixup; args are <= 0, outputs in [0,1])
__device__ __forceinline__ float fexp2(float x) { return __builtin_amdgcn_exp2f(x); }

// gfx950 cross-lane swaps via BUILTINS (not inline asm!).
// r5 lesson: raw asm permlane is schedule-dependent-broken (VALU->permlane
// hazard invisible through an asm blob); builtins emit real MIs so the
// backend inserts required wait states under any schedule.
__device__ __forceinline__ void plswap32(unsigned& a, unsigned& b) {
  uint2_t r = __builtin_amdgcn_permlane32_swap(a, b, false, false);
  a = r[0]; b = r[1];
}
__device__ __forceinline__ void plswap16(unsigned& a, unsigned& b) {
  uint2_t r = __builtin_amdgcn_permlane16_swap(a, b, false, false);
  a = r[0]; b = r[1];
}

// ---------------- fp32 -> fp16 convert ----------------
__global__ __launch_bounds__(256) void cvt_f32_f16(const float* __restrict__ in,
                                                   _Float16* __restrict__ out, int n) {
  int i = (blockIdx.x * 256 + threadIdx.x) * 8;
  if (i + 7 < n) {
    f32x4 a = *(const f32x4*)(in + i);
    f32x4 b = *(const f32x4*)(in + i + 4);
    half8 h;
    h[0] = (_Float16)a[0]; h[1] = (_Float16)a[1];
    h[2] = (_Float16)a[2]; h[3] = (_Float16)a[3];
    h[4] = (_Float16)b[0]; h[5] = (_Float16)b[1];
    h[6] = (_Float16)b[2]; h[7] = (_Float16)b[3];
    *(half8*)(out + i) = h;
  }
}

// 4 weight matrices (1M elems each) in one launch
__global__ __launch_bounds__(256) void cvt_w4(
    const float* __restrict__ a, const float* __restrict__ b,
    const float* __restrict__ c, const float* __restrict__ d,
    _Float16* __restrict__ oa, _Float16* __restrict__ ob,
    _Float16* __restrict__ oc, _Float16* __restrict__ od) {
  int seg = blockIdx.x >> 9;
  const float* src = (seg == 0) ? a : (seg == 1) ? b : (seg == 2) ? c : d;
  _Float16* dst = (seg == 0) ? oa : (seg == 1) ? ob : (seg == 2) ? oc : od;
  int i = ((blockIdx.x & 511) * 256 + threadIdx.x) * 8;
  f32x4 x0 = *(const f32x4*)(src + i);
  f32x4 x1 = *(const f32x4*)(src + i + 4);
  half8 h;
  h[0] = (_Float16)x0[0]; h[1] = (_Float16)x0[1];
  h[2] = (_Float16)x0[2]; h[3] = (_Float16)x0[3];
  h[4] = (_Float16)x1[0]; h[5] = (_Float16)x1[1];
  h[6] = (_Float16)x1[2]; h[7] = (_Float16)x1[3];
  *(half8*)(dst + i) = h;
}

// ---------------- shared 128x128x1024 NT-GEMM mainloop ----------------
// Double-buffered LDS, issue-early / sync-late (T3-minimum pipeline).
__device__ __forceinline__ void gemm128_mainloop(const _Float16* __restrict__ Ap,
                                                 const _Float16* __restrict__ Wp,
                                                 _Float16* As, _Float16* Bs,
                                                 f32x4 (&acc)[4][4]) {
  const int tid = threadIdx.x;
  const int lane = tid & 63;
  const int wid = tid >> 6;
  const int c = lane & 15, quad = lane >> 4;
  const int wm0 = (wid >> 1) * 64, wn0 = (wid & 1) * 64;
  const _Float16* ga0 = Ap + (size_t)(tid >> 2) * 1024 + (tid & 3) * 8;
  const _Float16* ga1 = ga0 + (size_t)64 * 1024;
  const _Float16* gb0 = Wp + (size_t)(tid >> 2) * 1024 + (tid & 3) * 8;
  const _Float16* gb1 = gb0 + (size_t)64 * 1024;
  // prologue: stage k0=0 into buffer 0
  async16(ga0, &As[tid * 8]);
  async16(ga1, &As[(tid + 256) * 8]);
  async16(gb0, &Bs[tid * 8]);
  async16(gb1, &Bs[(tid + 256) * 8]);
  __syncthreads();
  for (int k0 = 0; k0 < 1024; k0 += 32) {
    const int curo = ((k0 >> 5) & 1) * (128 * 32);
    if (k0 + 32 < 1024) {
      const int nxto = (128 * 32) - curo;
      async16(ga0 + k0 + 32, &As[nxto + tid * 8]);
      async16(ga1 + k0 + 32, &As[nxto + (tid + 256) * 8]);
      async16(gb0 + k0 + 32, &Bs[nxto + tid * 8]);
      async16(gb1 + k0 + 32, &Bs[nxto + (tid + 256) * 8]);
    }
    half8 af[4], bf[4];
#pragma unroll
    for (int i = 0; i < 4; ++i)
      af[i] = *(const half8*)&As[curo + (wm0 + i * 16 + c) * 32 + quad * 8];
#pragma unroll
    for (int j = 0; j < 4; ++j)
      bf[j] = *(const half8*)&Bs[curo + (wn0 + j * 16 + c) * 32 + quad * 8];
#pragma unroll
    for (int i = 0; i < 4; ++i)
#pragma unroll
      for (int j = 0; j < 4; ++j)
        acc[i][j] = __builtin_amdgcn_mfma_f32_16x16x32_f16(af[i], bf[j], acc[i][j], 0, 0, 0);
    __syncthreads();  // drains next-tile loads (issued a full compute phase ago)
  }
}

// ---------------- merged Q+K projection ----------------
// Q and K multiply the SAME A (xb): stage the A-tile once per K-step and do
// both MFMA sets against it (32 MFMA/barrier instead of 16). Per output tile
// this cuts staging 4->3 async16 and halves barrier count — the m97-structure
// is staging/barrier-bound, so the merged pair runs ~1.4x faster than two
// separate passes. Regs: acc_q+acc_k = 128 acc + ~90 arch, fits (256,2)'s
// 128/128 split. LDS 48KB -> 2 blocks/CU unchanged. Epilogue = r11-proven
// scatter (r12's LDS-staged epilogue was bank-conflicted and regressed).
__global__ __launch_bounds__(256, 2) void gemm_qk(
    const _Float16* __restrict__ A,
    const _Float16* __restrict__ Wq, const _Float16* __restrict__ Wk,
    const float* __restrict__ Bq, const float* __restrict__ Bk,
    _Float16* __restrict__ Qo, _Float16* __restrict__ Ko) {
  __shared__ __align__(16) _Float16 As[2 * 128 * 32];
  __shared__ __align__(16) _Float16 Bqs[2 * 128 * 32];
  __shared__ __align__(16) _Float16 Bks[2 * 128 * 32];
  const int tid = threadIdx.x;
  const int lane = tid & 63, wid = tid >> 6;
  const int c = lane & 15, quad = lane >> 4;
  const int wm0 = (wid >> 1) * 64, wn0 = (wid & 1) * 64;
  const int m0 = blockIdx.x * 128, n0 = blockIdx.y * 128;
  const _Float16* ga0 = A + (size_t)m0 * 1024 + (size_t)(tid >> 2) * 1024 + (tid & 3) * 8;
  const _Float16* ga1 = ga0 + (size_t)64 * 1024;
  const _Float16* gq0 = Wq + (size_t)n0 * 1024 + (size_t)(tid >> 2) * 1024 + (tid & 3) * 8;
  const _Float16* gq1 = gq0 + (size_t)64 * 1024;
  const _Float16* gk0 = Wk + (size_t)n0 * 1024 + (size_t)(tid >> 2) * 1024 + (tid & 3) * 8;
  const _Float16* gk1 = gk0 + (size_t)64 * 1024;
  // prologue: stage k0=0 into buffer 0
  async16(ga0, &As[tid * 8]);
  async16(ga1, &As[(tid + 256) * 8]);
  async16(gq0, &Bqs[tid * 8]);
  async16(gq1, &Bqs[(tid + 256) * 8]);
  async16(gk0, &Bks[tid * 8]);
  async16(gk1, &Bks[(tid + 256) * 8]);
  __syncthreads();
  f32x4 aq[4][4] = {}, ak[4][4] = {};
  for (int k0 = 0; k0 < 1024; k0 += 32) {
    const int curo = ((k0 >> 5) & 1) * (128 * 32);
    if (k0 + 32 < 1024) {
      const int nxto = (128 * 32) - curo;
      async16(ga0 + k0 + 32, &As[nxto + tid * 8]);
      async16(ga1 + k0 + 32, &As[nxto + (tid + 256) * 8]);
      async16(gq0 + k0 + 32, &Bqs[nxto + tid * 8]);
      async16(gq1 + k0 + 32, &Bqs[nxto + (tid + 256) * 8]);
      async16(gk0 + k0 + 32, &Bks[nxto + tid * 8]);
      async16(gk1 + k0 + 32, &Bks[nxto + (tid + 256) * 8]);
    }
    half8 af[4], bq[4], bk[4];
#pragma unroll
    for (int i = 0; i < 4; ++i)
      af[i] = *(const half8*)&As[curo + (wm0 + i * 16 + c) * 32 + quad * 8];
#pragma unroll
    for (int j = 0; j < 4; ++j)
      bq[j] = *(const half8*)&Bqs[curo + (wn0 + j * 16 + c) * 32 + quad * 8];
#pragma unroll
    for (int j = 0; j < 4; ++j)
      bk[j] = *(const half8*)&Bks[curo + (wn0 + j * 16 + c) * 32 + quad * 8];
#pragma unroll
    for (int i = 0; i < 4; ++i)
#pragma unroll
      for (int j = 0; j < 4; ++j) {
        aq[i][j] = __builtin_amdgcn_mfma_f32_16x16x32_f16(af[i], bq[j], aq[i][j], 0, 0, 0);
        ak[i][j] = __builtin_amdgcn_mfma_f32_16x16x32_f16(af[i], bk[j], ak[i][j], 0, 0, 0);
      }
    __syncthreads();  // drains next-tile loads (issued a full compute phase ago)
  }
  // epilogue: r11-proven scatter, x2 (Q gets the exp->exp2 LOG2E fold)
#pragma unroll
  for (int j = 0; j < 4; ++j) {
    int n = n0 + wn0 + j * 16 + c;
    float bvq = Bq[n], bvk = Bk[n];
    int h = n >> 6, d = n & 63;
#pragma unroll
    for (int i = 0; i < 4; ++i) {
      int mb = m0 + wm0 + i * 16 + quad * 4;
#pragma unroll
      for (int r = 0; r < 4; ++r) {
        int m = mb + r;
        int bb = m >> 12, t = m & 4095;
        size_t base = (((size_t)(bb * 16 + h) * 4096 + t) << 6) + d;
        Qo[base] = (_Float16)((aq[i][j][r] + bvq) * LOG2E);
        Ko[base] = (_Float16)(ak[i][j][r] + bvk);
      }
    }
  }
}

// ---------------- V projection: output TRANSPOSED (B,H,64,T) ----------------
__global__ __launch_bounds__(256, 2) void gemm_v(
    const _Float16* __restrict__ A, const _Float16* __restrict__ Wv,
    const float* __restrict__ Bv, _Float16* __restrict__ VoT) {
  __shared__ __align__(16) _Float16 As[2 * 128 * 32];
  __shared__ __align__(16) _Float16 Bs[2 * 128 * 32];
  const int m0 = blockIdx.x * 128, n0 = blockIdx.y * 128;
  f32x4 acc[4][4] = {};
  gemm128_mainloop(A + (size_t)m0 * 1024, Wv + (size_t)n0 * 1024, As, Bs, acc);
  const int tid = threadIdx.x;
  const int lane = tid & 63, wid = tid >> 6;
  const int c = lane & 15, quad = lane >> 4;
  const int wm0 = (wid >> 1) * 64, wn0 = (wid & 1) * 64;
#pragma unroll
  for (int j = 0; j < 4; ++j) {
    int n = n0 + wn0 + j * 16 + c;
    float bvv = Bv[n];
    int h = n >> 6, d = n & 63;
#pragma unroll
    for (int i = 0; i < 4; ++i) {
      int mb = m0 + wm0 + i * 16 + quad * 4;
      int bb = mb >> 12, t = mb & 4095;
      half4_t hv;
#pragma unroll
      for (int r = 0; r < 4; ++r) hv[r] = (_Float16)(acc[i][j][r] + bvv);
      *(half4_t*)&VoT[(((size_t)((bb * 16 + h) * 64 + d)) << 12) + t] = hv;
    }
  }
}

// ---------------- out projection, fp32 epilogue ----------------
// fp32 rows: lane-contiguous 64B segments, no amplification — left as-is.
__global__ __launch_bounds__(256, 2) void gemm_out(
    const _Float16* __restrict__ A, const _Float16* __restrict__ W,
    const float* __restrict__ bias, float* __restrict__ out) {
  __shared__ __align__(16) _Float16 As[2 * 128 * 32];
  __shared__ __align__(16) _Float16 Bs[2 * 128 * 32];
  const int m0 = blockIdx.x * 128, n0 = blockIdx.y * 128;
  f32x4 acc[4][4] = {};
  gemm128_mainloop(A + (size_t)m0 * 1024, W + (size_t)n0 * 1024, As, Bs, acc);
  const int tid = threadIdx.x;
  const int lane = tid & 63, wid = tid >> 6;
  const int c = lane & 15, quad = lane >> 4;
  const int wm0 = (wid >> 1) * 64, wn0 = (wid & 1) * 64;
#pragma unroll
  for (int j = 0; j < 4; ++j) {
    int n = n0 + wn0 + j * 16 + c;
    float bv = bias[n];
#pragma unroll
    for (int i = 0; i < 4; ++i) {
      int mb = m0 + wm0 + i * 16 + quad * 4;
#pragma unroll
      for (int r = 0; r < 4; ++r) {
        int m = mb + r;
        out[(size_t)m * 1024 + n] = acc[i][j][r] + bv;
      }
    }
  }
}

// ---------------- fa tile step: compute buf CB, prefetch j+1 into buf NB ----
// CB/NB are template constants so LDS addresses fold into the 16-bit DS
// offset immediates (r9 lesson: runtime offsets cost +5 VALUBusy pts, +25us).
// L row-sum on the MATRIX pipe: one extra PV MFMA per ks-chunk with an
// all-ones B operand accumulates lacc[r] = sum_k P[q=quad*4+r][k] in C/D
// layout = the epilogue's layout (r11).
template <int CB, int NB>
__device__ __forceinline__ void fa_step(
    int j, int tid, int c, int quad,
    const _Float16* __restrict__ Kh, const _Float16* __restrict__ Vh,
    _Float16* Ks, _Float16* VsT,
    const half8 (&qf)[2], f32x4 (&oacc)[4], float& M, f32x4& L4) {
  // prefetch tile j+1 into the other buffer (its readers finished before the
  // previous iteration's end barrier)
  if (j + 1 < 32) {
#pragma unroll
    for (int it = 0; it < 2; ++it) {
      int cidx = it * 512 + tid;
      int row = cidx >> 3, ck = (cidx & 7) ^ (row & 7);
      async16(Kh + (size_t)((j + 1) * 128 + row) * 64 + ck * 8, &Ks[NB + cidx * 8]);
    }
#pragma unroll
    for (int it = 0; it < 2; ++it) {
      int cidx = it * 512 + tid;
      int d = cidx >> 4, ck = (cidx & 15) ^ (d & 7);
      async16(Vh + (size_t)d * 4096 + (j + 1) * 128 + ck * 8, &VsT[NB + cidx * 8]);
    }
  }

  // S^T = K * Q^T (128 keys x 16 q-rows)
  f32x4 s[8];
#pragma unroll
  for (int j8 = 0; j8 < 8; ++j8) {
    int krow = j8 * 16 + c;
    int ck = quad ^ (c & 7);
    half8 kf = *(const half8*)&Ks[CB + krow * 64 + ck * 8];
    f32x4 z = {};
    s[j8] = __builtin_amdgcn_mfma_f32_16x16x32_f16(kf, qf[0], z, 0, 0, 0);
  }
#pragma unroll
  for (int j8 = 0; j8 < 8; ++j8) {
    int krow = j8 * 16 + c;
    int ck = (4 + quad) ^ (c & 7);
    half8 kf = *(const half8*)&Ks[CB + krow * 64 + ck * 8];
    s[j8] = __builtin_amdgcn_mfma_f32_16x16x32_f16(kf, qf[1], s[j8], 0, 0, 0);
  }

  // running max (max3 tree + cross-quad); M/al are per-lane for row c
  f32x4 t0 = vmax4_3(s[0], s[1], s[2]);
  f32x4 t1 = vmax4_3(s[3], s[4], s[5]);
  f32x4 t2 = vmax4_3(t0, t1, vmax4(s[6], s[7]));
  float mx = fmaxf(fmaxf(fmaxf(t2[0], t2[1]), t2[2]), t2[3]);
  mx = fmaxf(mx, __shfl_xor(mx, 16));
  mx = fmaxf(mx, __shfl_xor(mx, 32));
  float Mn = fmaxf(M, mx);
  float al = fexp2(M - Mn);
  M = Mn;

  const half8 vones = {(_Float16)1.f, (_Float16)1.f, (_Float16)1.f, (_Float16)1.f,
                       (_Float16)1.f, (_Float16)1.f, (_Float16)1.f, (_Float16)1.f};
  f32x4 lacc = {};  // row-sum accumulator (matrix pipe), row = quad*4+r

  // exp + pack + in-register transpose (permlane) + PV, 32 keys per chunk
#pragma unroll
  for (int ks = 0; ks < 4; ++ks) {
    f32x4 a0 = s[2 * ks] - Mn;
    f32x4 a1 = s[2 * ks + 1] - Mn;
    f32x4 p0, p1;
    p0[0] = fexp2(a0[0]); p0[1] = fexp2(a0[1]);
    p0[2] = fexp2(a0[2]); p0[3] = fexp2(a0[3]);
    p1[0] = fexp2(a1[0]); p1[1] = fexp2(a1[1]);
    p1[2] = fexp2(a1[2]); p1[3] = fexp2(a1[3]);
    unsigned w0 = __builtin_bit_cast(unsigned, pk_cvt(p0[0], p0[1]));
    unsigned w1 = __builtin_bit_cast(unsigned, pk_cvt(p0[2], p0[3]));
    unsigned w2 = __builtin_bit_cast(unsigned, pk_cvt(p1[0], p1[1]));
    unsigned w3 = __builtin_bit_cast(unsigned, pk_cvt(p1[2], p1[3]));
    plswap32(w0, w2);
    plswap32(w1, w3);
    plswap16(w0, w2);
    plswap16(w1, w3);
    uint4_t uw = {w0, w1, w2, w3};
    half8 pf = __builtin_bit_cast(half8, uw);
    lacc = __builtin_amdgcn_mfma_f32_16x16x32_f16(pf, vones, lacc, 0, 0, 0);
#pragma unroll
    for (int n = 0; n < 4; ++n) {
      int d = n * 16 + c;
      int ck = (ks * 4 + quad) ^ (d & 7);
      half8 vf = *(const half8*)&VsT[CB + d * 128 + ck * 8];
      oacc[n] = __builtin_amdgcn_mfma_f32_16x16x32_f16(pf, vf, oacc[n], 0, 0, 0);
    }
  }

  // L recursion per row (L4[r] tracks row quad*4+r; al held by lane quad*4+r)
#pragma unroll
  for (int r = 0; r < 4; ++r) {
    float alr = __shfl(al, quad * 4 + r);
    L4[r] = alr * L4[r] + lacc[r];  // L IS rescaled; O is NOT (faithful to reference)
  }

  __syncthreads();  // drains the j+1 prefetch (issued a full compute ago);
                    // joins all waves' reads of buf CB before it's reused
}

// ---------------- fused flash attention (buggy-variant-faithful) ----------------
// K/V double-buffer with compile-time buffer offsets (unroll-by-2), 1
// barrier/iter, 8 waves x 16 q-rows, 512 threads, LDS 64KB -> 2 blocks/CU,
// permlane P-transpose, matrix-pipe L row-sum, XCD swizzle, coalesced
// epilogue, raw exp2, KVBLK=128 (semantics: running-max sequence matches
// reference BKV scan).
__global__ __launch_bounds__(512, 4) void fa_kernel(
    const _Float16* __restrict__ Qg, const _Float16* __restrict__ Kg,
    const _Float16* __restrict__ VgT, _Float16* __restrict__ Og) {
  __shared__ __align__(16) _Float16 Ks[2 * 128 * 64];   // dbuf K; buf1 holds Q at start; buf0 = O staging at end
  __shared__ __align__(16) _Float16 VsT[2 * 64 * 128];  // dbuf V (d, key), swizzled

  const int tid = threadIdx.x;
  const int lane = tid & 63, wid = tid >> 6;   // wid 0..7
  const int c = lane & 15, quad = lane >> 4;
  // XCD-aware remap: xcd = bid&7 gets swz in [xcd*256, xcd*256+256) =
  // heads [xcd*8, xcd*8+8), all 32 qt each. Bijective (2048 % 8 == 0).
  const int bid = blockIdx.x;
  const int swz = (bid & 7) * 256 + (bid >> 3);
  const int bh = swz >> 5, qt = swz & 31;
  const int b = bh >> 4, h = bh & 15;
  const size_t hoff = (size_t)bh * 4096 * 64;
  const _Float16* Qh = Qg + hoff + (size_t)qt * 128 * 64;
  const _Float16* Kh = Kg + hoff;
  const _Float16* Vh = VgT + hoff;  // (64, 4096)

  // stage Q tile (128x64) into Ks BUF1, per-row chunk swizzle (512 thr -> 2 its)
#pragma unroll
  for (int it = 0; it < 2; ++it) {
    int cidx = it * 512 + tid;
    int row = cidx >> 3, ck = (cidx & 7) ^ (row & 7);
    async16(Qh + row * 64 + ck * 8, &Ks[8192 + cidx * 8]);
  }
  __syncthreads();

  const int wq0 = wid * 16;  // this wave's 16 q-rows
  half8 qf[2];
#pragma unroll
  for (int kk = 0; kk < 2; ++kk) {
    int row = wq0 + c;
    int ck = (kk * 4 + quad) ^ (c & 7);
    qf[kk] = *(const half8*)&Ks[8192 + row * 64 + ck * 8];
  }

  // issue K/V(0) into buf0 (no race with buf1 Q reads above)
#pragma unroll
  for (int it = 0; it < 2; ++it) {
    int cidx = it * 512 + tid;
    int row = cidx >> 3, ck = (cidx & 7) ^ (row & 7);
    async16(Kh + (size_t)row * 64 + ck * 8, &Ks[cidx * 8]);
  }
#pragma unroll
  for (int it = 0; it < 2; ++it) {
    int cidx = it * 512 + tid;
    int d = cidx >> 4, ck = (cidx & 15) ^ (d & 7);
    async16(Vh + (size_t)d * 4096 + ck * 8, &VsT[cidx * 8]);
  }
  __syncthreads();  // drains K/V(0); all waves done reading Q from buf1

  f32x4 oacc[4] = {};
  f32x4 L4 = {};
  float M = -__builtin_inff();

  for (int jj = 0; jj < 16; ++jj) {
    fa_step<0, 8192>(2 * jj, tid, c, quad, Kh, Vh, Ks, VsT, qf, oacc, M, L4);
    fa_step<8192, 0>(2 * jj + 1, tid, c, quad, Kh, Vh, Ks, VsT, qf, oacc, M, L4);
  }

  // ---- epilogue: O/L, staged through Ks buf0 for coalesced 128B-row stores ----
  // L4[r] already holds L for row quad*4+r (same layout as oacc) — no shfl.
#pragma unroll
  for (int r = 0; r < 4; ++r) {
    float inv = 1.0f / L4[r];
    int row = wq0 + quad * 4 + r;
#pragma unroll
    for (int n = 0; n < 4; ++n)
      Ks[row * 64 + n * 16 + c] = (_Float16)(oacc[n][r] * inv);
  }
  __syncthreads();
  {
    int row = tid >> 2, part = tid & 3;  // 512 threads: 4 threads per 128B row
    int t = qt * 128 + row;
    size_t base = (((size_t)(b * 4096 + t)) << 10) + h * 64 + part * 16;
    const half8* srcp = (const half8*)&Ks[row * 64 + part * 16];
    half8* dstp = (half8*)(Og + base);
    dstp[0] = srcp[0];
    dstp[1] = srcp[1];
  }
}

// ---------------- launcher ----------------
extern "C" void kernel_launch(void* const* d_in, const int* in_sizes, int n_in,
                              void* d_out, int out_size, void* d_ws, size_t ws_size,
                              hipStream_t stream) {
  const float* x = (const float*)d_in[0];
  const float* wq = (const float*)d_in[1];
  const float* bq = (const float*)d_in[2];
  const float* wk = (const float*)d_in[3];
  const float* bk = (const float*)d_in[4];
  const float* wv = (const float*)d_in[5];
  const float* bv = (const float*)d_in[6];
  const float* wo = (const float*)d_in[7];
  const float* bo = (const float*)d_in[8];

  char* ws = (char*)d_ws;
  const size_t MB = 1024 * 1024;
  _Float16* xb = (_Float16*)(ws);               // 32MB; dead after projections -> reused as Oatt
  _Float16* wq16 = (_Float16*)(ws + 32 * MB);
  _Float16* wk16 = (_Float16*)(ws + 34 * MB);
  _Float16* wv16 = (_Float16*)(ws + 36 * MB);
  _Float16* wo16 = (_Float16*)(ws + 38 * MB);
  _Float16* Qg = (_Float16*)(ws + 40 * MB);     // (B,H,T,64)
  _Float16* Kg = (_Float16*)(ws + 72 * MB);     // (B,H,T,64)
  _Float16* VgT = (_Float16*)(ws + 104 * MB);   // (B,H,64,T) written directly by gemm_v
  _Float16* Oatt = xb;                          // (B,T,1024)

  cvt_f32_f16<<<8192, 256, 0, stream>>>(x, xb, 16777216);
  cvt_w4<<<2048, 256, 0, stream>>>(wq, wk, wv, wo, wq16, wk16, wv16, wo16);

  gemm_qk<<<dim3(128, 8), 256, 0, stream>>>(xb, wq16, wk16, bq, bk, Qg, Kg);
  gemm_v<<<dim3(128, 8), 256, 0, stream>>>(xb, wv16, bv, VgT);
  fa_kernel<<<dim3(2048), 512, 0, stream>>>(Qg, Kg, VgT, Oatt);
  gemm_out<<<dim3(128, 8), 256, 0, stream>>>(Oatt, wo16, bo, (float*)d_out);
}

// Round 14
// 654.395 us; speedup vs baseline: 1.0653x; 1.0329x over previous
//
#include <hip/hip_runtime.h>
#include <cstdint>
#include <cstddef>

typedef _Float16 half8 __attribute__((ext_vector_type(8)));
typedef _Float16 half4_t __attribute__((ext_vector_type(4)));
typedef _Float16 half2_t __attribute__((ext_vector_type(2)));
typedef float f32x4 __attribute__((ext_vector_type(4)));
typedef unsigned int uint4_t __attribute__((ext_vector_type(4)));
typedef unsigned int uint2_t __attribute__((ext_vector_type(2)));

#define LOG2E 1.4426950408889634f

// async global->LDS, 16B per lane. LDS dest must be wave-uniform base + lane*16.
__device__ __forceinline__ void async16(const void* g, void* l) {
  __builtin_amdgcn_global_load_lds((const __attribute__((address_space(1))) void*)g,
                                   (__attribute__((address_space(3))) void*)l,
                                   16, 0, 0);
}

__device__ __forceinline__ f32x4 vmax4(f32x4 a, f32x4 b) {
  f32x4 r;
  r[0] = fmaxf(a[0], b[0]); r[1] = fmaxf(a[1], b[1]);
  r[2] = fmaxf(a[2], b[2]); r[3] = fmaxf(a[3], b[3]);
  return r;
}

// fmaxf(fmaxf(a,b),c) fuses to v_max3_f32
__device__ __forceinline__ f32x4 vmax4_3(f32x4 a, f32x4 b, f32x4 c) {
  f32x4 r;
  r[0] = fmaxf(fmaxf(a[0], b[0]), c[0]);
  r[1] = fmaxf(fmaxf(a[1], b[1]), c[1]);
  r[2] = fmaxf(fmaxf(a[2], b[2]), c[2]);
  r[3] = fmaxf(fmaxf(a[3], b[3]), c[3]);
  return r;
}

__device__ __forceinline__ half2_t pk_cvt(float a, float b) {
  return __builtin_bit_cast(half2_t, __builtin_amdgcn_cvt_pkrtz(a, b));
}

// raw v_exp_f32 (skips OCML denormal fixup; args are <= 0, outputs in [0,1])
__device__ __forceinline__ float fexp2(float x) { return __builtin_amdgcn_exp2f(x); }

// gfx950 cross-lane swaps via BUILTINS (not inline asm!).
// r5 lesson: raw asm permlane is schedule-dependent-broken (VALU->permlane
// hazard invisible through an asm blob); builtins emit real MIs so the
// backend inserts required wait states under any schedule.
__device__ __forceinline__ void plswap32(unsigned& a, unsigned& b) {
  uint2_t r = __builtin_amdgcn_permlane32_swap(a, b, false, false);
  a = r[0]; b = r[1];
}
__device__ __forceinline__ void plswap16(unsigned& a, unsigned& b) {
  uint2_t r = __builtin_amdgcn_permlane16_swap(a, b, false, false);
  a = r[0]; b = r[1];
}

// ---------------- fp32 -> fp16 convert ----------------
__global__ __launch_bounds__(256) void cvt_f32_f16(const float* __restrict__ in,
                                                   _Float16* __restrict__ out, int n) {
  int i = (blockIdx.x * 256 + threadIdx.x) * 8;
  if (i + 7 < n) {
    f32x4 a = *(const f32x4*)(in + i);
    f32x4 b = *(const f32x4*)(in + i + 4);
    half8 h;
    h[0] = (_Float16)a[0]; h[1] = (_Float16)a[1];
    h[2] = (_Float16)a[2]; h[3] = (_Float16)a[3];
    h[4] = (_Float16)b[0]; h[5] = (_Float16)b[1];
    h[6] = (_Float16)b[2]; h[7] = (_Float16)b[3];
    *(half8*)(out + i) = h;
  }
}

// 4 weight matrices (1M elems each) in one launch
__global__ __launch_bounds__(256) void cvt_w4(
    const float* __restrict__ a, const float* __restrict__ b,
    const float* __restrict__ c, const float* __restrict__ d,
    _Float16* __restrict__ oa, _Float16* __restrict__ ob,
    _Float16* __restrict__ oc, _Float16* __restrict__ od) {
  int seg = blockIdx.x >> 9;
  const float* src = (seg == 0) ? a : (seg == 1) ? b : (seg == 2) ? c : d;
  _Float16* dst = (seg == 0) ? oa : (seg == 1) ? ob : (seg == 2) ? oc : od;
  int i = ((blockIdx.x & 511) * 256 + threadIdx.x) * 8;
  f32x4 x0 = *(const f32x4*)(src + i);
  f32x4 x1 = *(const f32x4*)(src + i + 4);
  half8 h;
  h[0] = (_Float16)x0[0]; h[1] = (_Float16)x0[1];
  h[2] = (_Float16)x0[2]; h[3] = (_Float16)x0[3];
  h[4] = (_Float16)x1[0]; h[5] = (_Float16)x1[1];
  h[6] = (_Float16)x1[2]; h[7] = (_Float16)x1[3];
  *(half8*)(dst + i) = h;
}

// ---------------- shared 128x128x1024 NT-GEMM mainloop ----------------
// Double-buffered LDS, issue-early / sync-late (T3-minimum pipeline).
__device__ __forceinline__ void gemm128_mainloop(const _Float16* __restrict__ Ap,
                                                 const _Float16* __restrict__ Wp,
                                                 _Float16* As, _Float16* Bs,
                                                 f32x4 (&acc)[4][4]) {
  const int tid = threadIdx.x;
  const int lane = tid & 63;
  const int wid = tid >> 6;
  const int c = lane & 15, quad = lane >> 4;
  const int wm0 = (wid >> 1) * 64, wn0 = (wid & 1) * 64;
  const _Float16* ga0 = Ap + (size_t)(tid >> 2) * 1024 + (tid & 3) * 8;
  const _Float16* ga1 = ga0 + (size_t)64 * 1024;
  const _Float16* gb0 = Wp + (size_t)(tid >> 2) * 1024 + (tid & 3) * 8;
  const _Float16* gb1 = gb0 + (size_t)64 * 1024;
  // prologue: stage k0=0 into buffer 0
  async16(ga0, &As[tid * 8]);
  async16(ga1, &As[(tid + 256) * 8]);
  async16(gb0, &Bs[tid * 8]);
  async16(gb1, &Bs[(tid + 256) * 8]);
  __syncthreads();
  for (int k0 = 0; k0 < 1024; k0 += 32) {
    const int curo = ((k0 >> 5) & 1) * (128 * 32);
    if (k0 + 32 < 1024) {
      const int nxto = (128 * 32) - curo;
      async16(ga0 + k0 + 32, &As[nxto + tid * 8]);
      async16(ga1 + k0 + 32, &As[nxto + (tid + 256) * 8]);
      async16(gb0 + k0 + 32, &Bs[nxto + tid * 8]);
      async16(gb1 + k0 + 32, &Bs[nxto + (tid + 256) * 8]);
    }
    half8 af[4], bf[4];
#pragma unroll
    for (int i = 0; i < 4; ++i)
      af[i] = *(const half8*)&As[curo + (wm0 + i * 16 + c) * 32 + quad * 8];
#pragma unroll
    for (int j = 0; j < 4; ++j)
      bf[j] = *(const half8*)&Bs[curo + (wn0 + j * 16 + c) * 32 + quad * 8];
#pragma unroll
    for (int i = 0; i < 4; ++i)
#pragma unroll
      for (int j = 0; j < 4; ++j)
        acc[i][j] = __builtin_amdgcn_mfma_f32_16x16x32_f16(af[i], bf[j], acc[i][j], 0, 0, 0);
    __syncthreads();  // drains next-tile loads (issued a full compute phase ago)
  }
}

// ---------------- QKV projection ----------------
// z=0/1: scatter to (B,H,T,64); z=2: V stored directly TRANSPOSED (B,H,64,T).
// Round-14: XCD-aware remap (T1 for gemm). Old grid order put the 24 blocks
// sharing an A-panel (same m; different n,z) 128+ dispatch slots apart ->
// different XCDs, panel re-reads from L3/HBM, latency exposed in the
// end-of-iter barrier drain. Now each XCD owns 16 contiguous m-panels and
// walks (n,z) fastest: A-panel reused by 24 CONSECUTIVE same-XCD blocks ->
// L2-hot (~200cyc vs ~400-900). Bijective (3072 % 8 == 0). Epilogue =
// r11-proven scatter.
__global__ __launch_bounds__(256, 2) void gemm_qkv(
    const _Float16* __restrict__ A,
    const _Float16* __restrict__ Wq, const _Float16* __restrict__ Wk,
    const _Float16* __restrict__ Wv,
    const float* __restrict__ Bq, const float* __restrict__ Bk,
    const float* __restrict__ Bv,
    _Float16* __restrict__ Qo, _Float16* __restrict__ Ko, _Float16* __restrict__ VoT) {
  __shared__ __align__(16) _Float16 As[2 * 128 * 32];
  __shared__ __align__(16) _Float16 Bs[2 * 128 * 32];
  // XCD swizzle: bidlin -> (xcd, ml, yz); m-tile = xcd*16+ml, (n,z) = yz
  const int bidlin = blockIdx.x + 128 * (blockIdx.y + 8 * blockIdx.z);
  const int xcd = bidlin & 7, idx = bidlin >> 3;   // idx 0..383
  const int ml = idx / 24, yz = idx % 24;          // ml 0..15, yz 0..23
  const int z = yz >> 3, y = yz & 7;
  const int m0 = (xcd * 16 + ml) * 128, n0 = y * 128;
  const _Float16* W = (z == 0) ? Wq : (z == 1) ? Wk : Wv;
  const float* bias = (z == 0) ? Bq : (z == 1) ? Bk : Bv;
  const float scale = (z == 0) ? LOG2E : 1.0f;  // fold exp->exp2 into Q
  f32x4 acc[4][4] = {};
  gemm128_mainloop(A + (size_t)m0 * 1024, W + (size_t)n0 * 1024, As, Bs, acc);
  const int tid = threadIdx.x;
  const int lane = tid & 63, wid = tid >> 6;
  const int c = lane & 15, quad = lane >> 4;
  const int wm0 = (wid >> 1) * 64, wn0 = (wid & 1) * 64;
  if (z == 2) {
#pragma unroll
    for (int j = 0; j < 4; ++j) {
      int n = n0 + wn0 + j * 16 + c;
      float bvv = bias[n];
      int h = n >> 6, d = n & 63;
#pragma unroll
      for (int i = 0; i < 4; ++i) {
        int mb = m0 + wm0 + i * 16 + quad * 4;
        int bb = mb >> 12, t = mb & 4095;
        half4_t hv;
#pragma unroll
        for (int r = 0; r < 4; ++r) hv[r] = (_Float16)(acc[i][j][r] + bvv);
        *(half4_t*)&VoT[(((size_t)((bb * 16 + h) * 64 + d)) << 12) + t] = hv;
      }
    }
  } else {
    _Float16* out = (z == 0) ? Qo : Ko;
#pragma unroll
    for (int j = 0; j < 4; ++j) {
      int n = n0 + wn0 + j * 16 + c;
      float bvv = bias[n];
      int h = n >> 6, d = n & 63;
#pragma unroll
      for (int i = 0; i < 4; ++i) {
        int mb = m0 + wm0 + i * 16 + quad * 4;
#pragma unroll
        for (int r = 0; r < 4; ++r) {
          int m = mb + r;
          float v = (acc[i][j][r] + bvv) * scale;
          int bb = m >> 12, t = m & 4095;
          out[(((size_t)(bb * 16 + h) * 4096 + t) << 6) + d] = (_Float16)v;
        }
      }
    }
  }
}

// ---------------- out projection, fp32 epilogue ----------------
// fp32 rows: lane-contiguous 64B segments, no amplification. XCD remap:
// each XCD owns 16 m-panels x 8 n; wo16 (2MB) goes L2-resident per XCD.
__global__ __launch_bounds__(256, 2) void gemm_out(
    const _Float16* __restrict__ A, const _Float16* __restrict__ W,
    const float* __restrict__ bias, float* __restrict__ out) {
  __shared__ __align__(16) _Float16 As[2 * 128 * 32];
  __shared__ __align__(16) _Float16 Bs[2 * 128 * 32];
  const int bidlin = blockIdx.x + 128 * blockIdx.y;
  const int xcd = bidlin & 7, idx = bidlin >> 3;   // idx 0..127
  const int ml = idx >> 3, y = idx & 7;            // ml 0..15
  const int m0 = (xcd * 16 + ml) * 128, n0 = y * 128;
  f32x4 acc[4][4] = {};
  gemm128_mainloop(A + (size_t)m0 * 1024, W + (size_t)n0 * 1024, As, Bs, acc);
  const int tid = threadIdx.x;
  const int lane = tid & 63, wid = tid >> 6;
  const int c = lane & 15, quad = lane >> 4;
  const int wm0 = (wid >> 1) * 64, wn0 = (wid & 1) * 64;
#pragma unroll
  for (int j = 0; j < 4; ++j) {
    int n = n0 + wn0 + j * 16 + c;
    float bv = bias[n];
#pragma unroll
    for (int i = 0; i < 4; ++i) {
      int mb = m0 + wm0 + i * 16 + quad * 4;
#pragma unroll
      for (int r = 0; r < 4; ++r) {
        int m = mb + r;
        out[(size_t)m * 1024 + n] = acc[i][j][r] + bv;
      }
    }
  }
}

// ---------------- fa tile step: compute buf CB, prefetch j+1 into buf NB ----
// CB/NB are template constants so LDS addresses fold into the 16-bit DS
// offset immediates (r9 lesson: runtime offsets cost +5 VALUBusy pts, +25us).
// L row-sum on the MATRIX pipe: one extra PV MFMA per ks-chunk with an
// all-ones B operand accumulates lacc[r] = sum_k P[q=quad*4+r][k] in C/D
// layout = the epilogue's layout (r11).
template <int CB, int NB>
__device__ __forceinline__ void fa_step(
    int j, int tid, int c, int quad,
    const _Float16* __restrict__ Kh, const _Float16* __restrict__ Vh,
    _Float16* Ks, _Float16* VsT,
    const half8 (&qf)[2], f32x4 (&oacc)[4], float& M, f32x4& L4) {
  // prefetch tile j+1 into the other buffer (its readers finished before the
  // previous iteration's end barrier)
  if (j + 1 < 32) {
#pragma unroll
    for (int it = 0; it < 2; ++it) {
      int cidx = it * 512 + tid;
      int row = cidx >> 3, ck = (cidx & 7) ^ (row & 7);
      async16(Kh + (size_t)((j + 1) * 128 + row) * 64 + ck * 8, &Ks[NB + cidx * 8]);
    }
#pragma unroll
    for (int it = 0; it < 2; ++it) {
      int cidx = it * 512 + tid;
      int d = cidx >> 4, ck = (cidx & 15) ^ (d & 7);
      async16(Vh + (size_t)d * 4096 + (j + 1) * 128 + ck * 8, &VsT[NB + cidx * 8]);
    }
  }

  // S^T = K * Q^T (128 keys x 16 q-rows)
  f32x4 s[8];
#pragma unroll
  for (int j8 = 0; j8 < 8; ++j8) {
    int krow = j8 * 16 + c;
    int ck = quad ^ (c & 7);
    half8 kf = *(const half8*)&Ks[CB + krow * 64 + ck * 8];
    f32x4 z = {};
    s[j8] = __builtin_amdgcn_mfma_f32_16x16x32_f16(kf, qf[0], z, 0, 0, 0);
  }
#pragma unroll
  for (int j8 = 0; j8 < 8; ++j8) {
    int krow = j8 * 16 + c;
    int ck = (4 + quad) ^ (c & 7);
    half8 kf = *(const half8*)&Ks[CB + krow * 64 + ck * 8];
    s[j8] = __builtin_amdgcn_mfma_f32_16x16x32_f16(kf, qf[1], s[j8], 0, 0, 0);
  }

  // running max (max3 tree + cross-quad); M/al are per-lane for row c
  f32x4 t0 = vmax4_3(s[0], s[1], s[2]);
  f32x4 t1 = vmax4_3(s[3], s[4], s[5]);
  f32x4 t2 = vmax4_3(t0, t1, vmax4(s[6], s[7]));
  float mx = fmaxf(fmaxf(fmaxf(t2[0], t2[1]), t2[2]), t2[3]);
  mx = fmaxf(mx, __shfl_xor(mx, 16));
  mx = fmaxf(mx, __shfl_xor(mx, 32));
  float Mn = fmaxf(M, mx);
  float al = fexp2(M - Mn);
  M = Mn;

  const half8 vones = {(_Float16)1.f, (_Float16)1.f, (_Float16)1.f, (_Float16)1.f,
                       (_Float16)1.f, (_Float16)1.f, (_Float16)1.f, (_Float16)1.f};
  f32x4 lacc = {};  // row-sum accumulator (matrix pipe), row = quad*4+r

  // exp + pack + in-register transpose (permlane) + PV, 32 keys per chunk
#pragma unroll
  for (int ks = 0; ks < 4; ++ks) {
    f32x4 a0 = s[2 * ks] - Mn;
    f32x4 a1 = s[2 * ks + 1] - Mn;
    f32x4 p0, p1;
    p0[0] = fexp2(a0[0]); p0[1] = fexp2(a0[1]);
    p0[2] = fexp2(a0[2]); p0[3] = fexp2(a0[3]);
    p1[0] = fexp2(a1[0]); p1[1] = fexp2(a1[1]);
    p1[2] = fexp2(a1[2]); p1[3] = fexp2(a1[3]);
    unsigned w0 = __builtin_bit_cast(unsigned, pk_cvt(p0[0], p0[1]));
    unsigned w1 = __builtin_bit_cast(unsigned, pk_cvt(p0[2], p0[3]));
    unsigned w2 = __builtin_bit_cast(unsigned, pk_cvt(p1[0], p1[1]));
    unsigned w3 = __builtin_bit_cast(unsigned, pk_cvt(p1[2], p1[3]));
    plswap32(w0, w2);
    plswap32(w1, w3);
    plswap16(w0, w2);
    plswap16(w1, w3);
    uint4_t uw = {w0, w1, w2, w3};
    half8 pf = __builtin_bit_cast(half8, uw);
    lacc = __builtin_amdgcn_mfma_f32_16x16x32_f16(pf, vones, lacc, 0, 0, 0);
#pragma unroll
    for (int n = 0; n < 4; ++n) {
      int d = n * 16 + c;
      int ck = (ks * 4 + quad) ^ (d & 7);
      half8 vf = *(const half8*)&VsT[CB + d * 128 + ck * 8];
      oacc[n] = __builtin_amdgcn_mfma_f32_16x16x32_f16(pf, vf, oacc[n], 0, 0, 0);
    }
  }

  // L recursion per row (L4[r] tracks row quad*4+r; al held by lane quad*4+r)
#pragma unroll
  for (int r = 0; r < 4; ++r) {
    float alr = __shfl(al, quad * 4 + r);
    L4[r] = alr * L4[r] + lacc[r];  // L IS rescaled; O is NOT (faithful to reference)
  }

  __syncthreads();  // drains the j+1 prefetch (issued a full compute ago);
                    // joins all waves' reads of buf CB before it's reused
}

// ---------------- fused flash attention (buggy-variant-faithful) ----------------
// K/V double-buffer with compile-time buffer offsets (unroll-by-2), 1
// barrier/iter, 8 waves x 16 q-rows, 512 threads, LDS 64KB -> 2 blocks/CU,
// permlane P-transpose, matrix-pipe L row-sum, XCD swizzle, coalesced
// epilogue, raw exp2, KVBLK=128 (semantics: running-max sequence matches
// reference BKV scan).
__global__ __launch_bounds__(512, 4) void fa_kernel(
    const _Float16* __restrict__ Qg, const _Float16* __restrict__ Kg,
    const _Float16* __restrict__ VgT, _Float16* __restrict__ Og) {
  __shared__ __align__(16) _Float16 Ks[2 * 128 * 64];   // dbuf K; buf1 holds Q at start; buf0 = O staging at end
  __shared__ __align__(16) _Float16 VsT[2 * 64 * 128];  // dbuf V (d, key), swizzled

  const int tid = threadIdx.x;
  const int lane = tid & 63, wid = tid >> 6;   // wid 0..7
  const int c = lane & 15, quad = lane >> 4;
  // XCD-aware remap: xcd = bid&7 gets swz in [xcd*256, xcd*256+256) =
  // heads [xcd*8, xcd*8+8), all 32 qt each. Bijective (2048 % 8 == 0).
  const int bid = blockIdx.x;
  const int swz = (bid & 7) * 256 + (bid >> 3);
  const int bh = swz >> 5, qt = swz & 31;
  const int b = bh >> 4, h = bh & 15;
  const size_t hoff = (size_t)bh * 4096 * 64;
  const _Float16* Qh = Qg + hoff + (size_t)qt * 128 * 64;
  const _Float16* Kh = Kg + hoff;
  const _Float16* Vh = VgT + hoff;  // (64, 4096)

  // stage Q tile (128x64) into Ks BUF1, per-row chunk swizzle (512 thr -> 2 its)
#pragma unroll
  for (int it = 0; it < 2; ++it) {
    int cidx = it * 512 + tid;
    int row = cidx >> 3, ck = (cidx & 7) ^ (row & 7);
    async16(Qh + row * 64 + ck * 8, &Ks[8192 + cidx * 8]);
  }
  __syncthreads();

  const int wq0 = wid * 16;  // this wave's 16 q-rows
  half8 qf[2];
#pragma unroll
  for (int kk = 0; kk < 2; ++kk) {
    int row = wq0 + c;
    int ck = (kk * 4 + quad) ^ (c & 7);
    qf[kk] = *(const half8*)&Ks[8192 + row * 64 + ck * 8];
  }

  // issue K/V(0) into buf0 (no race with buf1 Q reads above)
#pragma unroll
  for (int it = 0; it < 2; ++it) {
    int cidx = it * 512 + tid;
    int row = cidx >> 3, ck = (cidx & 7) ^ (row & 7);
    async16(Kh + (size_t)row * 64 + ck * 8, &Ks[cidx * 8]);
  }
#pragma unroll
  for (int it = 0; it < 2; ++it) {
    int cidx = it * 512 + tid;
    int d = cidx >> 4, ck = (cidx & 15) ^ (d & 7);
    async16(Vh + (size_t)d * 4096 + ck * 8, &VsT[cidx * 8]);
  }
  __syncthreads();  // drains K/V(0); all waves done reading Q from buf1

  f32x4 oacc[4] = {};
  f32x4 L4 = {};
  float M = -__builtin_inff();

  for (int jj = 0; jj < 16; ++jj) {
    fa_step<0, 8192>(2 * jj, tid, c, quad, Kh, Vh, Ks, VsT, qf, oacc, M, L4);
    fa_step<8192, 0>(2 * jj + 1, tid, c, quad, Kh, Vh, Ks, VsT, qf, oacc, M, L4);
  }

  // ---- epilogue: O/L, staged through Ks buf0 for coalesced 128B-row stores ----
  // L4[r] already holds L for row quad*4+r (same layout as oacc) — no shfl.
#pragma unroll
  for (int r = 0; r < 4; ++r) {
    float inv = 1.0f / L4[r];
    int row = wq0 + quad * 4 + r;
#pragma unroll
    for (int n = 0; n < 4; ++n)
      Ks[row * 64 + n * 16 + c] = (_Float16)(oacc[n][r] * inv);
  }
  __syncthreads();
  {
    int row = tid >> 2, part = tid & 3;  // 512 threads: 4 threads per 128B row
    int t = qt * 128 + row;
    size_t base = (((size_t)(b * 4096 + t)) << 10) + h * 64 + part * 16;
    const half8* srcp = (const half8*)&Ks[row * 64 + part * 16];
    half8* dstp = (half8*)(Og + base);
    dstp[0] = srcp[0];
    dstp[1] = srcp[1];
  }
}

// ---------------- launcher ----------------
extern "C" void kernel_launch(void* const* d_in, const int* in_sizes, int n_in,
                              void* d_out, int out_size, void* d_ws, size_t ws_size,
                              hipStream_t stream) {
  const float* x = (const float*)d_in[0];
  const float* wq = (const float*)d_in[1];
  const float* bq = (const float*)d_in[2];
  const float* wk = (const float*)d_in[3];
  const float* bk = (const float*)d_in[4];
  const float* wv = (const float*)d_in[5];
  const float* bv = (const float*)d_in[6];
  const float* wo = (const float*)d_in[7];
  const float* bo = (const float*)d_in[8];

  char* ws = (char*)d_ws;
  const size_t MB = 1024 * 1024;
  _Float16* xb = (_Float16*)(ws);               // 32MB; dead after gemm_qkv -> reused as Oatt
  _Float16* wq16 = (_Float16*)(ws + 32 * MB);
  _Float16* wk16 = (_Float16*)(ws + 34 * MB);
  _Float16* wv16 = (_Float16*)(ws + 36 * MB);
  _Float16* wo16 = (_Float16*)(ws + 38 * MB);
  _Float16* Qg = (_Float16*)(ws + 40 * MB);     // (B,H,T,64)
  _Float16* Kg = (_Float16*)(ws + 72 * MB);     // (B,H,T,64)
  _Float16* VgT = (_Float16*)(ws + 104 * MB);   // (B,H,64,T) written directly by gemm_qkv
  _Float16* Oatt = xb;                          // (B,T,1024)

  cvt_f32_f16<<<8192, 256, 0, stream>>>(x, xb, 16777216);
  cvt_w4<<<2048, 256, 0, stream>>>(wq, wk, wv, wo, wq16, wk16, wv16, wo16);

  gemm_qkv<<<dim3(128, 8, 3), 256, 0, stream>>>(xb, wq16, wk16, wv16,
                                                bq, bk, bv, Qg, Kg, VgT);
  fa_kernel<<<dim3(2048), 512, 0, stream>>>(Qg, Kg, VgT, Oatt);
  gemm_out<<<dim3(128, 8), 256, 0, stream>>>(Oatt, wo16, bo, (float*)d_out);
}